// Round 4
// baseline (197.649 us; speedup 1.0000x reference)
//
#include <hip/hip_runtime.h>
#include <math.h>

#define DIM 192
#define OD  191          // output domain per axis (191^3 outputs)
#define VOLX 7077888     // 192^3
#define TW 32            // output tile width (2 voxels per thread in w)
#define TH 16
#define NBW 6            // ceil(191/32)
#define NBH 12           // ceil(191/16)
#define CD  10           // d-planes per chunk
#define NCH 20           // 20*10=200 >= 191

typedef _Float16 h4 __attribute__((ext_vector_type(4)));
typedef _Float16 h8 __attribute__((ext_vector_type(8)));
typedef unsigned int u2v __attribute__((ext_vector_type(2)));

static __device__ __forceinline__ h4 habs4(h4 v) {
    u2v u = __builtin_bit_cast(u2v, v);
    u &= 0x7FFF7FFFu;
    return __builtin_bit_cast(h4, u);
}

// Fused: diff -> 3x3x3 box mean -> neo-hookean energy -> mean reduction.
// f16 raw planes in a 2-deep LDS ring; diffs packed {H012_,D012_} h8 + {W012_} h4;
// each thread emits 2 adjacent-w voxels (shared window taps); W sums pair-read b128.
__global__ __launch_bounds__(256, 4)
void nh_fused_kernel(const float* __restrict__ P, float* __restrict__ out) {
    const int tid = threadIdx.x;
    const int tx  = tid & 15;        // w-pair index
    const int ty  = tid >> 4;        // h within tile
    const int w0  = blockIdx.x * TW;
    const int h0  = blockIdx.y * TH;
    const int ds  = blockIdx.z * CD;
    const int de  = min(ds + CD, OD);

    __shared__ h4 sraw[2][19][36];   // raw f16, 3ch per point; 19x35 used, pad 36
    __shared__ h8 sHD[18][35];       // {H0,H1,H2,0, D0,D1,D2,0}; stride 35*16B (12 dw mod 32)
    __shared__ h4 sW[18][38];        // {W0,W1,W2,0}; stride 38*8B = 304B (16B-aligned, 12 dw mod 32)
    __shared__ float wsum[4];

    const int oh  = h0 + ty;
    const int ow0 = w0 + 2 * tx;
    const bool v0 = (oh < OD) && (ow0 < OD);
    const bool v1 = (oh < OD) && (ow0 + 1 < OD);
    const bool interior = (w0 >= 1) && (w0 + 33 <= OD) && (h0 >= 1) && (h0 + 17 <= OD);

    // ring of per-plane 2D window sums, 2 outputs each
    h8 rA0[2], rA1[2], rA2[2];
    h4 rW0[2], rW1[2], rW2[2];
    #pragma unroll
    for (int o = 0; o < 2; ++o) {
        rA0[o] = (h8)0; rA1[o] = (h8)0; rA2[o] = (h8)0;
        rW0[o] = (h4)0; rW1[o] = (h4)0; rW2[o] = (h4)0;
    }

    float acc = 0.f;

    for (int t = ds - 1; t <= de + 1; ++t) {
        const int cb = t & 1, pb = cb ^ 1;
        __syncthreads();   // protect LDS from previous iteration's readers

        // (a) stage raw plane t as f16 into ring buffer cb
        if (t >= 0 && t < DIM) {
            const size_t pl = (size_t)t * (DIM * DIM);
            if (interior) {
                #pragma unroll
                for (int it = 0; it < 3; ++it) {
                    const int l = tid + it * 256;
                    if (l < 19 * 35) {
                        const int hh = l / 35, ww = l - hh * 35;
                        const size_t base = pl + (size_t)(h0 - 1 + hh) * DIM + (size_t)(w0 - 1 + ww);
                        const float x = P[base], y = P[base + VOLX], z = P[base + 2 * VOLX];
                        sraw[cb][hh][ww] = (h4){(_Float16)x, (_Float16)y, (_Float16)z, (_Float16)0.f};
                    }
                }
            } else {
                #pragma unroll
                for (int it = 0; it < 3; ++it) {
                    const int l = tid + it * 256;
                    if (l < 19 * 35) {
                        const int hh = l / 35, ww = l - hh * 35;
                        const int hp = h0 - 1 + hh, wp = w0 - 1 + ww;
                        float x = 0.f, y = 0.f, z = 0.f;
                        if (hp >= 0 && hp < DIM && wp >= 0 && wp < DIM) {
                            const size_t base = pl + (size_t)hp * DIM + (size_t)wp;
                            x = P[base]; y = P[base + VOLX]; z = P[base + 2 * VOLX];
                        }
                        sraw[cb][hh][ww] = (h4){(_Float16)x, (_Float16)y, (_Float16)z, (_Float16)0.f};
                    }
                }
            }
        }
        __syncthreads();

        // (b) build packed f16 diff plane p = t-1 (prev buffer = plane p, cur = p+1)
        const int p = t - 1;
        const bool pp = (t >= ds) && (p >= 0) && (p < OD);
        if (pp) {
            #pragma unroll
            for (int it = 0; it < 3; ++it) {
                const int l = tid + it * 256;
                if (l < 18 * 34) {
                    const int hh = l / 34, ww = l - hh * 34;
                    const h4 c = sraw[pb][hh][ww];
                    h4 hd = habs4(sraw[pb][hh + 1][ww] - c);   // H-diff
                    h4 wd = habs4(sraw[pb][hh][ww + 1] - c);   // W-diff
                    h4 dd = habs4(sraw[cb][hh][ww] - c);       // D-diff
                    if (!interior) {
                        const int hp = h0 - 1 + hh, wp = w0 - 1 + ww;
                        if (hp < 0 || hp >= OD || wp < 0 || wp >= OD) {
                            hd = (h4)0; dd = (h4)0; wd = (h4)0;
                        }
                    }
                    sHD[hh][ww] = __builtin_shufflevector(hd, dd, 0, 1, 2, 3, 4, 5, 6, 7);
                    sW[hh][ww]  = wd;
                }
            }
        }
        __syncthreads();

        // (c) 3x3 2D window sums for the 2 outputs; rotate ring
        #pragma unroll
        for (int o = 0; o < 2; ++o) {
            rA0[o] = rA1[o]; rA1[o] = rA2[o];
            rW0[o] = rW1[o]; rW1[o] = rW2[o];
        }
        if (pp) {
            h8 s0 = (h8)0, s1 = (h8)0;
            h4 q0 = (h4)0, q1 = (h4)0;
            #pragma unroll
            for (int j = 0; j < 3; ++j) {
                const h8 t0 = sHD[ty + j][2 * tx + 0];
                const h8 t1 = sHD[ty + j][2 * tx + 1];
                const h8 t2 = sHD[ty + j][2 * tx + 2];
                const h8 t3 = sHD[ty + j][2 * tx + 3];
                const h8 m = t1 + t2;
                s0 += t0 + m;
                s1 += t3 + m;
                // W sums: pair-read 2 points per b128 (16B-aligned rows)
                const h8* rw = (const h8*)&sW[ty + j][2 * tx];
                const h8 u01 = rw[0];
                const h8 u23 = rw[1];
                const h4 u0 = __builtin_shufflevector(u01, u01, 0, 1, 2, 3);
                const h4 u1 = __builtin_shufflevector(u01, u01, 4, 5, 6, 7);
                const h4 u2 = __builtin_shufflevector(u23, u23, 0, 1, 2, 3);
                const h4 u3 = __builtin_shufflevector(u23, u23, 4, 5, 6, 7);
                const h4 mw = u1 + u2;
                q0 += u0 + mw;
                q1 += u3 + mw;
            }
            rA2[0] = s0; rA2[1] = s1; rW2[0] = q0; rW2[1] = q1;
        } else {
            rA2[0] = (h8)0; rA2[1] = (h8)0; rW2[0] = (h4)0; rW2[1] = (h4)0;
        }

        // (d) emit output voxel plane d = t-2 (needs diff planes d-1,d,d+1)
        const int d = t - 2;
        if (d >= ds && d < de) {
            #pragma unroll
            for (int o = 0; o < 2; ++o) {
                if (o == 0 ? v0 : v1) {
                    const h8 FA = rA0[o] + rA1[o] + rA2[o];
                    const h4 FW = rW0[o] + rW1[o] + rW2[o];
                    const float inv27 = 1.f / 27.f;
                    const float dydx = (float)FA[0] * inv27, dxdx = (float)FA[1] * inv27, dzdx = (float)FA[2] * inv27;
                    const float dydy = (float)FA[4] * inv27, dxdy = (float)FA[5] * inv27, dzdy = (float)FA[6] * inv27;
                    const float dydz = (float)FW[0] * inv27, dxdz = (float)FW[1] * inv27, dzdz = (float)FW[2] * inv27;
                    const float a = dxdx + 1.f, e = dydy + 1.f, iN = dzdz + 1.f;
                    const float J = a * (e * iN - dydz * dzdy)
                                  - dxdy * (dydx * iN - dydz * dzdx)
                                  + dxdz * (dydx * dzdy - e * dzdx);
                    const float Tr = a * a + dxdy * dxdy + dxdz * dxdz
                                   + dydx * dydx + e * e + dydz * dydz
                                   + dzdx * dzdx + dzdy * dzdy + iN * iN;
                    const float stretch = Tr * __expf(1.f - J) - 3.f;
                    const float vol = (J - 1.f) * (J - 1.f);
                    // mu=1,lam=5 -> U = (1/12)*stretch + (15/31)*vol (verified rounds 1-3)
                    acc += 0.0833333358f * stretch + 0.4838709677f * vol;
                }
            }
        }
    }

    // mean scaling (191^3)
    acc *= (1.f / 6967871.f);

    // wave reduce (64 lanes), then block reduce, one atomic per block
    #pragma unroll
    for (int off = 32; off > 0; off >>= 1) acc += __shfl_down(acc, off, 64);
    if ((tid & 63) == 0) wsum[tid >> 6] = acc;
    __syncthreads();
    if (tid == 0) {
        atomicAdd(out, wsum[0] + wsum[1] + wsum[2] + wsum[3]);
    }
}

extern "C" void kernel_launch(void* const* d_in, const int* in_sizes, int n_in,
                              void* d_out, int out_size, void* d_ws, size_t ws_size,
                              hipStream_t stream) {
    const float* y_pred = (const float*)d_in[0];
    float* out = (float*)d_out;

    // d_out is poisoned 0xAA before every timed launch — zero it (graph-capturable).
    hipMemsetAsync(out, 0, sizeof(float), stream);

    dim3 grid(NBW, NBH, NCH);
    nh_fused_kernel<<<grid, 256, 0, stream>>>(y_pred, out);
}

// Round 5
// 195.000 us; speedup vs baseline: 1.0136x; 1.0136x over previous
//
#include <hip/hip_runtime.h>
#include <math.h>

#define DIM 192
#define OD  191          // output domain per axis (191^3 outputs)
#define PLN 36864        // 192^2
#define VOLX 7077888     // 192^3
#define TW 16
#define TH 16
#define NBH 12           // ceil(191/16)
#define CD  8            // d-planes per chunk
#define NCH 24           // 24*8 = 192 >= 191

typedef _Float16 h4 __attribute__((ext_vector_type(4)));
typedef _Float16 h8 __attribute__((ext_vector_type(8)));
typedef unsigned int u2v __attribute__((ext_vector_type(2)));

static __device__ __forceinline__ h4 habs4(h4 v) {
    u2v u = __builtin_bit_cast(u2v, v);
    u &= 0x7FFF7FFFu;
    return __builtin_bit_cast(h4, u);
}

// Fused: diff -> 3x3x3 box mean -> neo-hookean energy -> mean reduction.
// Software-pipelined: plane t+1 prefetched to REGISTERS while computing plane t;
// sraw 3-ring + double-buffered diff arrays => ONE barrier per plane and no
// global-latency -> barrier serialization.
__global__ __launch_bounds__(256, 6)
void nh_fused_kernel(const float* __restrict__ P, float* __restrict__ out) {
    const int tid = threadIdx.x;
    const int tx = tid & 15, ty = tid >> 4;
    const int w0 = blockIdx.x * TW, h0 = blockIdx.y * TH;
    const int ds = blockIdx.z * CD;
    const int de = min(ds + CD, OD);
    const int LP = min(de + 1, DIM - 1);   // last raw plane index ever needed

    __shared__ h4 sraw[3][19][19];         // raw f16 {c0,c1,c2,0}; 3-plane ring
    __shared__ h8 sA[2][18][19];           // {H0,H1,H2,0, D0,D1,D2,0}; double-buffered
    __shared__ h4 sW[2][18][19];           // {W0,W1,W2,0}; double-buffered
    __shared__ float wsum[4];

    const bool valid = (h0 + ty < OD) && (w0 + tx < OD);

    // ---- hoisted staging descriptors (19x19 = 361 points, <=2 per thread) ----
    const int sh0 = tid / 19, sw0_ = tid - sh0 * 19;
    const int shp0 = h0 - 1 + sh0, swp0 = w0 - 1 + sw0_;
    const bool sm0 = (shp0 >= 0) && (shp0 < DIM) && (swp0 >= 0) && (swp0 < DIM);
    const int soff0 = min(max(shp0, 0), DIM - 1) * DIM + min(max(swp0, 0), DIM - 1);
    const bool sact1 = tid < 105;          // 361 - 256
    const int sl1 = min(tid + 256, 360);
    const int sh1 = sl1 / 19, sw1_ = sl1 - sh1 * 19;
    const int shp1 = h0 - 1 + sh1, swp1 = w0 - 1 + sw1_;
    const bool sm1 = (shp1 >= 0) && (shp1 < DIM) && (swp1 >= 0) && (swp1 < DIM);
    const int soff1 = min(max(shp1, 0), DIM - 1) * DIM + min(max(swp1, 0), DIM - 1);

    // ---- hoisted diff-item descriptors (18x18 = 324 items, <=2 per thread) ----
    const int dh0 = tid / 18, dw0 = tid - dh0 * 18;
    const bool dz0 = ((h0 - 1 + dh0) < 0) || ((h0 - 1 + dh0) >= OD) ||
                     ((w0 - 1 + dw0) < 0) || ((w0 - 1 + dw0) >= OD);
    const bool dact1 = tid < 68;           // 324 - 256
    const int dl1 = min(tid + 256, 323);
    const int dh1 = dl1 / 18, dw1 = dl1 - dh1 * 18;
    const bool dz1 = ((h0 - 1 + dh1) < 0) || ((h0 - 1 + dh1) >= OD) ||
                     ((w0 - 1 + dw1) < 0) || ((w0 - 1 + dw1) >= OD);

    // in-flight prefetch registers (one raw plane, 3 channels, 2 points)
    float Ax0 = 0.f, Ay0 = 0.f, Az0 = 0.f, Ax1 = 0.f, Ay1 = 0.f, Az1 = 0.f;

    auto issue = [&](int q) {
        const float* b0 = P + (size_t)q * PLN + soff0;
        Ax0 = b0[0]; Ay0 = b0[VOLX]; Az0 = b0[2 * VOLX];
        if (sact1) {
            const float* b1 = P + (size_t)q * PLN + soff1;
            Ax1 = b1[0]; Ay1 = b1[VOLX]; Az1 = b1[2 * VOLX];
        }
    };
    auto store = [&](int slot) {
        h4 v0 = sm0 ? (h4){(_Float16)Ax0, (_Float16)Ay0, (_Float16)Az0, (_Float16)0.f} : (h4)0;
        sraw[slot][sh0][sw0_] = v0;
        if (sact1) {
            h4 v1 = sm1 ? (h4){(_Float16)Ax1, (_Float16)Ay1, (_Float16)Az1, (_Float16)0.f} : (h4)0;
            sraw[slot][sh1][sw1_] = v1;
        }
    };

    // ---- prologue: prime planes ds-1, ds; leave ds+1 in flight ----
    if (ds >= 1) { issue(ds - 1); store((ds + 2) % 3); }
    issue(ds);  store(ds % 3);
    issue(ds + 1);                         // ds+1 <= LP always
    __syncthreads();

    h8 rA0 = (h8)0, rA1 = (h8)0, rA2 = (h8)0;
    h4 rW0 = (h4)0, rW1 = (h4)0, rW2 = (h4)0;
    float acc = 0.f;

    for (int t = ds; t <= de + 2; ++t) {
        const int pb3 = (t + 2) % 3, cb3 = t % 3, db = t & 1;

        // phase b: diffs of plane p = t-1 -> buffer db (reads ring planes t-1, t)
        if (t <= de + 1) {
            const int p = t - 1;
            const bool pv = (p >= 0) && (p < OD);
            {
                h4 hd = (h4)0, wd = (h4)0, dd = (h4)0;
                if (pv) {
                    const h4 c = sraw[pb3][dh0][dw0];
                    hd = habs4(sraw[pb3][dh0 + 1][dw0] - c);
                    wd = habs4(sraw[pb3][dh0][dw0 + 1] - c);
                    dd = habs4(sraw[cb3][dh0][dw0] - c);
                    if (dz0) { hd = (h4)0; wd = (h4)0; dd = (h4)0; }
                }
                sA[db][dh0][dw0] = __builtin_shufflevector(hd, dd, 0, 1, 2, 3, 4, 5, 6, 7);
                sW[db][dh0][dw0] = wd;
            }
            if (dact1) {
                h4 hd = (h4)0, wd = (h4)0, dd = (h4)0;
                if (pv) {
                    const h4 c = sraw[pb3][dh1][dw1];
                    hd = habs4(sraw[pb3][dh1 + 1][dw1] - c);
                    wd = habs4(sraw[pb3][dh1][dw1 + 1] - c);
                    dd = habs4(sraw[cb3][dh1][dw1] - c);
                    if (dz1) { hd = (h4)0; wd = (h4)0; dd = (h4)0; }
                }
                sA[db][dh1][dw1] = __builtin_shufflevector(hd, dd, 0, 1, 2, 3, 4, 5, 6, 7);
                sW[db][dh1][dw1] = wd;
            }
        }

        // phase c: 3x3 window sums from the OTHER diff buffer (written last iter)
        rA0 = rA1; rA1 = rA2; rW0 = rW1; rW1 = rW2;
        if (t >= ds + 1) {
            const int rb = (t - 1) & 1;
            h8 s = (h8)0; h4 q = (h4)0;
            #pragma unroll
            for (int j = 0; j < 3; ++j) {
                #pragma unroll
                for (int k = 0; k < 3; ++k) {
                    s += sA[rb][ty + j][tx + k];
                    q += sW[rb][ty + j][tx + k];
                }
            }
            rA2 = s; rW2 = q;
        } else { rA2 = (h8)0; rW2 = (h4)0; }

        // emit output plane d = t-3 (window = wsum(d-1), wsum(d), wsum(d+1))
        const int d = t - 3;
        if (valid && d >= ds) {
            const h8 FA = rA0 + rA1 + rA2;
            const h4 FW = rW0 + rW1 + rW2;
            const float inv27 = 1.f / 27.f;
            const float dydx = (float)FA[0] * inv27, dxdx = (float)FA[1] * inv27, dzdx = (float)FA[2] * inv27;
            const float dydy = (float)FA[4] * inv27, dxdy = (float)FA[5] * inv27, dzdy = (float)FA[6] * inv27;
            const float dydz = (float)FW[0] * inv27, dxdz = (float)FW[1] * inv27, dzdz = (float)FW[2] * inv27;
            const float a = dxdx + 1.f, e = dydy + 1.f, iN = dzdz + 1.f;
            const float J = a * (e * iN - dydz * dzdy)
                          - dxdy * (dydx * iN - dydz * dzdx)
                          + dxdz * (dydx * dzdy - e * dzdx);
            const float Tr = a * a + dxdy * dxdy + dxdz * dxdz
                           + dydx * dydx + e * e + dydz * dydz
                           + dzdx * dzdx + dzdy * dzdy + iN * iN;
            const float stretch = Tr * __expf(1.f - J) - 3.f;
            const float vol = (J - 1.f) * (J - 1.f);
            // mu=1,lam=5 -> U = (1/12)*stretch + (15/31)*vol (verified rounds 1-4)
            acc += 0.0833333358f * stretch + 0.4838709677f * vol;
        }

        // drain prefetch of plane t+1 into the ring slot that held plane t-2,
        // then launch the next prefetch (plane t+2)
        if (t + 1 <= LP) store((t + 1) % 3);
        if (t + 2 <= LP) issue(t + 2);
        __syncthreads();
    }

    // mean scaling (191^3)
    acc *= (1.f / 6967871.f);

    // wave reduce (64 lanes), then block reduce, one atomic per block
    #pragma unroll
    for (int off = 32; off > 0; off >>= 1) acc += __shfl_down(acc, off, 64);
    if ((tid & 63) == 0) wsum[tid >> 6] = acc;
    __syncthreads();
    if (tid == 0) {
        atomicAdd(out, wsum[0] + wsum[1] + wsum[2] + wsum[3]);
    }
}

extern "C" void kernel_launch(void* const* d_in, const int* in_sizes, int n_in,
                              void* d_out, int out_size, void* d_ws, size_t ws_size,
                              hipStream_t stream) {
    const float* y_pred = (const float*)d_in[0];
    float* out = (float*)d_out;

    // d_out is poisoned 0xAA before every timed launch — zero it (graph-capturable).
    hipMemsetAsync(out, 0, sizeof(float), stream);

    dim3 grid(NBH, NBH, NCH);
    nh_fused_kernel<<<grid, 256, 0, stream>>>(y_pred, out);
}

// Round 6
// 192.713 us; speedup vs baseline: 1.0256x; 1.0119x over previous
//
#include <hip/hip_runtime.h>
#include <math.h>

#define DIM 192
#define OD  191          // output domain per axis (191^3 outputs)
#define PLN 36864        // 192^2
#define VOLX 7077888     // 192^3
#define TW 32            // 2 voxels per thread in w
#define TH 16
#define NBW 6            // ceil(191/32)
#define NBH 12           // ceil(191/16)
#define CD  8
#define NCH 24           // 24*8 = 192 >= 191

#define RH 19            // raw halo rows   (h0-1 .. h0+17)
#define RW 35            // raw halo cols   (w0-1 .. w0+33)
#define NS (RH*RW)       // 665 staging points
#define DH 18            // diff rows       (h0-1 .. h0+16)
#define DW 34            // diff cols       (w0-1 .. w0+32)
#define ND (DH*DW)       // 612 diff points
#define SBW 34           // sB row stride (even -> b64-aligned pairs)

typedef _Float16 h2v __attribute__((ext_vector_type(2)));
typedef _Float16 h4  __attribute__((ext_vector_type(4)));
typedef _Float16 h8  __attribute__((ext_vector_type(8)));
typedef unsigned int u2v __attribute__((ext_vector_type(2)));

static __device__ __forceinline__ h4 habs4(h4 v) {
    u2v u = __builtin_bit_cast(u2v, v);
    u &= 0x7FFF7FFFu;
    return __builtin_bit_cast(h4, u);
}

// Fused: diff -> 3x3x3 box mean -> neo-hookean energy -> mean reduction.
// W=2 w-blocking: window reads 108 B/voxel (4xb128 + 2xb64 per row, shared
// middle taps). Raw planes f16 in a 2-ring, prefetched to registers one full
// plane ahead. Field packing: sA h8={H0,H1,H2,W0, D0,D1,D2,W1}, sB h2={W2,0}.
__global__ __launch_bounds__(256, 6)
void nh_fused_kernel(const float* __restrict__ P, float* __restrict__ out) {
    const int tid = threadIdx.x;
    const int tx = tid & 15, ty = tid >> 4;
    const int w0 = blockIdx.x * TW, h0 = blockIdx.y * TH;
    const int ds = blockIdx.z * CD;
    const int de = min(ds + CD, OD);
    const int lastP = min(de + 1, DIM - 1);   // last raw plane index needed

    __shared__ h4  sraw[2][RH][RW];   // raw f16 {c0,c1,c2,0}; 2-plane ring
    __shared__ h8  sA[DH][RW];        // {H0,H1,H2,W0, D0,D1,D2,W1}; stride 35 (140dw, bank-uniform)
    __shared__ h2v sB[DH][SBW];       // {W2,0}; stride 34 (b64-aligned pairs)
    __shared__ float wsum[4];

    const int oh = h0 + ty, ow0 = w0 + 2 * tx;
    const bool v0 = (oh < OD) && (ow0 < OD);
    const bool v1 = (oh < OD) && (ow0 + 1 < OD);

    // ---- hoisted staging descriptors (665 pts, <=3 per thread) ----
    int  sLin[3], sOff[3];
    bool sMask[3], sAct[3];
    #pragma unroll
    for (int i = 0; i < 3; ++i) {
        int l = tid + 256 * i;
        sAct[i] = (l < NS);
        l = min(l, NS - 1);
        const int sh = l / RW, sw = l - sh * RW;
        const int hp = h0 - 1 + sh, wp = w0 - 1 + sw;
        sMask[i] = (hp >= 0) && (hp < DIM) && (wp >= 0) && (wp < DIM);
        sOff[i]  = min(max(hp, 0), DIM - 1) * DIM + min(max(wp, 0), DIM - 1);
        sLin[i]  = l;                      // raw ring is stride-RW linear
    }

    // ---- hoisted diff-item descriptors (612 items, <=3 per thread) ----
    int  dLin[3], dLinB[3];
    bool dAct[3], dOut[3];
    #pragma unroll
    for (int i = 0; i < 3; ++i) {
        int l = tid + 256 * i;
        dAct[i] = (l < ND);
        l = min(l, ND - 1);
        const int dh = l / DW, dw = l - dh * DW;
        const int hp = h0 - 1 + dh, wp = w0 - 1 + dw;
        dOut[i]  = (hp < 0) || (hp >= OD) || (wp < 0) || (wp >= OD);
        dLin[i]  = dh * RW + dw;           // sA and sraw share stride RW
        dLinB[i] = dh * SBW + dw;
    }

    // in-flight prefetch registers (one raw plane, 3 channels, 3 items)
    float px[3][3];
    #pragma unroll
    for (int i = 0; i < 3; ++i) { px[i][0] = px[i][1] = px[i][2] = 0.f; }

    auto issue = [&](int q) {
        #pragma unroll
        for (int i = 0; i < 3; ++i) {
            if (sAct[i]) {
                const float* b = P + (size_t)q * PLN + sOff[i];
                px[i][0] = b[0]; px[i][1] = b[VOLX]; px[i][2] = b[2 * VOLX];
            }
        }
    };
    auto store = [&](int slot) {
        h4* dst = &sraw[slot][0][0];
        #pragma unroll
        for (int i = 0; i < 3; ++i) {
            if (sAct[i]) {
                h4 v = sMask[i] ? (h4){(_Float16)px[i][0], (_Float16)px[i][1],
                                       (_Float16)px[i][2], (_Float16)0.f}
                                : (h4)0;
                dst[sLin[i]] = v;
            }
        }
    };

    // ---- prologue: plane ds-1 staged; plane ds left in flight ----
    if (ds >= 1) { issue(ds - 1); store((ds - 1) & 1); }
    issue(ds);

    h8 rA0[2], rA1[2], rA2[2];
    _Float16 rB0[2], rB1[2], rB2[2];
    #pragma unroll
    for (int o = 0; o < 2; ++o) {
        rA0[o] = (h8)0; rA1[o] = (h8)0; rA2[o] = (h8)0;
        rB0[o] = (_Float16)0.f; rB1[o] = (_Float16)0.f; rB2[o] = (_Float16)0.f;
    }
    float acc = 0.f;

    for (int p = ds - 1; p <= de; ++p) {
        const int sp = p & 1, sn = sp ^ 1;
        const bool pv = (p >= 0) && (p < OD);

        // drain prefetch of plane p+1 into ring slot sn; issue plane p+2
        if (p + 1 <= lastP) store(sn);
        if (p + 2 <= lastP) issue(p + 2);
        __syncthreads();

        // phase b: diffs of plane p (reads raw p, p+1) -> sA/sB
        if (pv) {
            const h4* rp = &sraw[sp][0][0];
            const h4* rn = &sraw[sn][0][0];
            h8*  pA = &sA[0][0];
            h2v* pB = &sB[0][0];
            #pragma unroll
            for (int i = 0; i < 3; ++i) {
                if (dAct[i]) {
                    const int li = dLin[i];
                    const h4 c  = rp[li];
                    h4 hd = habs4(rp[li + RW] - c);   // H-diff
                    h4 wd = habs4(rp[li + 1]  - c);   // W-diff
                    h4 dd = habs4(rn[li]      - c);   // D-diff
                    if (dOut[i]) { hd = (h4)0; wd = (h4)0; dd = (h4)0; }
                    const h4 lo = __builtin_shufflevector(hd, wd, 0, 1, 2, 4);
                    const h4 hi = __builtin_shufflevector(dd, wd, 0, 1, 2, 5);
                    pA[li] = __builtin_shufflevector(lo, hi, 0, 1, 2, 3, 4, 5, 6, 7);
                    pB[dLinB[i]] = (h2v){wd[2], (_Float16)0.f};
                }
            }
        }
        __syncthreads();

        // phase c: 3x3 window sums for 2 outputs; rotate ring
        #pragma unroll
        for (int o = 0; o < 2; ++o) {
            rA0[o] = rA1[o]; rA1[o] = rA2[o];
            rB0[o] = rB1[o]; rB1[o] = rB2[o];
        }
        if (pv) {
            h8 s0 = (h8)0, s1 = (h8)0;
            _Float16 q0 = (_Float16)0.f, q1 = (_Float16)0.f;
            #pragma unroll
            for (int j = 0; j < 3; ++j) {
                const h8* rowA = &sA[ty + j][2 * tx];
                const h8 t0 = rowA[0], t1 = rowA[1], t2 = rowA[2], t3 = rowA[3];
                const h4* rowB = (const h4*)&sB[ty + j][2 * tx];
                const h4 u01 = rowB[0], u23 = rowB[1];   // {W2(c),0,W2(c+1),0} x2
                const h8 m = t1 + t2;
                s0 += t0 + m;
                s1 += t3 + m;
                const _Float16 mB = u01[2] + u23[0];
                q0 += u01[0] + mB;
                q1 += u23[2] + mB;
            }
            rA2[0] = s0; rA2[1] = s1; rB2[0] = q0; rB2[1] = q1;
        } else {
            rA2[0] = (h8)0; rA2[1] = (h8)0;
            rB2[0] = (_Float16)0.f; rB2[1] = (_Float16)0.f;
        }

        // emit output plane d = p-1 (wsums d-1,d,d+1 = rA0,rA1,rA2)
        const int d = p - 1;
        if (d >= ds) {
            #pragma unroll
            for (int o = 0; o < 2; ++o) {
                if (o == 0 ? v0 : v1) {
                    const h8 FA = rA0[o] + rA1[o] + rA2[o];
                    const float FBz = (float)(rB0[o] + rB1[o] + rB2[o]);
                    const float inv27 = 1.f / 27.f;
                    const float dydx = (float)FA[0] * inv27, dxdx = (float)FA[1] * inv27, dzdx = (float)FA[2] * inv27;
                    const float dydz = (float)FA[3] * inv27;                       // W0
                    const float dydy = (float)FA[4] * inv27, dxdy = (float)FA[5] * inv27, dzdy = (float)FA[6] * inv27;
                    const float dxdz = (float)FA[7] * inv27;                       // W1
                    const float dzdz = FBz * inv27;                                 // W2
                    const float a = dxdx + 1.f, e = dydy + 1.f, iN = dzdz + 1.f;
                    const float J = a * (e * iN - dydz * dzdy)
                                  - dxdy * (dydx * iN - dydz * dzdx)
                                  + dxdz * (dydx * dzdy - e * dzdx);
                    const float Tr = a * a + dxdy * dxdy + dxdz * dxdz
                                   + dydx * dydx + e * e + dydz * dydz
                                   + dzdx * dzdx + dzdy * dzdy + iN * iN;
                    const float stretch = Tr * __expf(1.f - J) - 3.f;
                    const float vol = (J - 1.f) * (J - 1.f);
                    // mu=1,lam=5 -> U = (1/12)*stretch + (15/31)*vol (verified R1-R5)
                    acc += 0.0833333358f * stretch + 0.4838709677f * vol;
                }
            }
        }
    }

    // mean scaling (191^3)
    acc *= (1.f / 6967871.f);

    // wave reduce (64 lanes), then block reduce, one atomic per block
    #pragma unroll
    for (int off = 32; off > 0; off >>= 1) acc += __shfl_down(acc, off, 64);
    if ((tid & 63) == 0) wsum[tid >> 6] = acc;
    __syncthreads();
    if (tid == 0) {
        atomicAdd(out, wsum[0] + wsum[1] + wsum[2] + wsum[3]);
    }
}

extern "C" void kernel_launch(void* const* d_in, const int* in_sizes, int n_in,
                              void* d_out, int out_size, void* d_ws, size_t ws_size,
                              hipStream_t stream) {
    const float* y_pred = (const float*)d_in[0];
    float* out = (float*)d_out;

    // d_out is poisoned 0xAA before every timed launch — zero it (graph-capturable).
    hipMemsetAsync(out, 0, sizeof(float), stream);

    dim3 grid(NBW, NBH, NCH);
    nh_fused_kernel<<<grid, 256, 0, stream>>>(y_pred, out);
}